// Round 2
// baseline (318.436 us; speedup 1.0000x reference)
//
#include <hip/hip_runtime.h>
#include <cstdint>
#include <cstddef>

#define B_TOT 16384
#define NSTEP 100

#define SQRT_H 0.1f
#define RH     2.0e-4f                 // R*h
#define MUH    6.0e-4f                 // MU*h
#define DRIFT  4.0e-4f                 // (MU - 0.5*SIG^2)*h
#define SIGC   0.2f
#define SSC    0.02f                   // SIGC*SQRT_H
#define INVBN  0.99950037468877324f    // 1/sqrt(1+1e-3)
#define QF     0.96078943915232318f    // exp(100*(R-MU)*h)
#define DISC   0.98019867330675525f    // exp(-R*T)
#define CURT   0.005f

typedef __attribute__((ext_vector_type(8))) short short8;
typedef __attribute__((ext_vector_type(4))) float floatx4;
typedef __attribute__((ext_vector_type(4))) unsigned uintx4;
typedef __attribute__((ext_vector_type(2))) unsigned uintx2;

__device__ __forceinline__ unsigned toSort(float f){
    unsigned u = __float_as_uint(f);
    return (u & 0x80000000u) ? ~u : (u | 0x80000000u);
}
__device__ __forceinline__ float fromSort(unsigned s){
    unsigned u = (s & 0x80000000u) ? (s & 0x7fffffffu) : ~s;
    return __uint_as_float(u);
}
__device__ __forceinline__ unsigned short bfc(float f){   // f32->bf16 RNE
    unsigned u = __float_as_uint(f);
    unsigned r = u + 0x7FFFu + ((u >> 16) & 1u);
    return (unsigned short)(r >> 16);
}
__device__ __forceinline__ float red16(float v){
    float t;
    t = __int_as_float(__builtin_amdgcn_update_dpp(0, __float_as_int(v), 0x128, 0xF, 0xF, false)); v += t;
    t = __int_as_float(__builtin_amdgcn_update_dpp(0, __float_as_int(v), 0x124, 0xF, 0xF, false)); v += t;
    t = __int_as_float(__builtin_amdgcn_update_dpp(0, __float_as_int(v), 0x122, 0xF, 0xF, false)); v += t;
    t = __int_as_float(__builtin_amdgcn_update_dpp(0, __float_as_int(v), 0x121, 0xF, 0xF, false)); v += t;
    return v;
}
__device__ __forceinline__ float tanh_fast(float z){
    z = fminf(9.f, fmaxf(-9.f, z));
    float e = __expf(2.f * z);
    return __fdividef(e - 1.f, e + 1.f);
}
__device__ __forceinline__ unsigned laneid(){
    return __builtin_amdgcn_mbcnt_hi(~0u, __builtin_amdgcn_mbcnt_lo(~0u, 0u));
}
// wave-aggregated LDS histogram add (handles heavy same-bin concentration)
__device__ __forceinline__ void aggAdd(unsigned* hist, unsigned bin){
    bool pending = true;
    unsigned lid = laneid();
    while (__any(pending)){
        if (pending){
            unsigned lead = (unsigned)__builtin_amdgcn_readfirstlane((int)bin);
            if (bin == lead){
                unsigned long long m = __ballot(1);
                if (lid == (unsigned)__builtin_ctzll(m))
                    atomicAdd(&hist[lead], (unsigned)__popcll(m));
                pending = false;
            }
        }
    }
}

// ---------------------------------------------------------------------------
// K0: fold BN scale/shift into weights, pre-convert to bf16.
// Split into 30 independent blocks: bid = p*3 + m, m in {W2, W3, Wout}.
// Per-output arithmetic identical to the previous fused version.
// ---------------------------------------------------------------------------
__global__ __launch_bounds__(256,1) void k_conv(
    const float* __restrict__ uWh, const float* __restrict__ ubh,
    const float* __restrict__ bng, const float* __restrict__ bnb,
    const float* __restrict__ uWout, const float* __restrict__ ubout,
    unsigned short* __restrict__ Wc2, unsigned short* __restrict__ Wc3,
    unsigned short* __restrict__ Wco,
    float* __restrict__ b2f, float* __restrict__ b3f, float* __restrict__ bof)
{
    const int bid = blockIdx.x;
    const int p = bid / 3, m = bid % 3;
    const int t = threadIdx.x;
    __shared__ float gs[64], es[64];
    __shared__ float red4[64][4];
    __shared__ float red8[32][8];
    if (t < 64){
        gs[t] = INVBN * bng[(p*3+m)*64 + t];
        es[t] = bnb[(p*3+m)*64 + t];
    }
    __syncthreads();
    if (m < 2){
        unsigned short* Wt = (m == 0) ? Wc2 : Wc3;
        const int j = t & 63, kq = t >> 6;
        float bs = 0.f;
        for (int k = kq*16; k < kq*16+16; ++k){
            float w = uWh[((size_t)(p*2+m)*64 + k)*64 + j];
            bs += w * es[k];
            Wt[(size_t)(p*64 + j)*64 + k] = bfc(w * gs[k]);
        }
        red4[j][kq] = bs;
        __syncthreads();
        if (t < 64){
            float v = ubh[(p*3+m+1)*64 + t]
                    + red4[t][0]+red4[t][1]+red4[t][2]+red4[t][3];
            if (m == 0) b2f[p*64 + t] = v; else b3f[p*64 + t] = v;
        }
    } else {
        const int d = t & 31, kq = t >> 5;
        float bs = 0.f;
        for (int k = kq*8; k < kq*8+8; ++k){
            float w = (d < 20) ? uWout[((size_t)p*64 + k)*20 + d] : 0.f;
            bs += w * es[k];
            Wco[(size_t)(p*32 + d)*64 + k] = bfc(w * gs[k]);
        }
        red8[d][kq] = bs;
        __syncthreads();
        if (t < 32){
            float s = 0.f;
            for (int q=0;q<8;q++) s += red8[t][q];
            bof[p*32 + t] = ((t < 20) ? ubout[p*20 + t] : 0.f) + s;
        }
    }
}

// ---------------------------------------------------------------------------
// K1: SDE scan + fused option-head partial reduction.
// 16 lanes/row; phase-invariant sum(u) hoisted; invS tracking (no divides);
// MLP via bf16 MFMA on pre-folded weights; phase-batched dW register
// prefetch (loads for phase p+1 issue before the MLP barriers).
// ---------------------------------------------------------------------------
__global__ __launch_bounds__(256, 4) void k_sim(
    const float* __restrict__ x_in, const float* __restrict__ S0,
    const float* __restrict__ dW,
    const float* __restrict__ u0W, const float* __restrict__ u0b,
    const float* __restrict__ uWin, const float* __restrict__ ubh,
    const unsigned short* __restrict__ Wc2, const unsigned short* __restrict__ Wc3,
    const unsigned short* __restrict__ Wco,
    const float* __restrict__ b2f, const float* __restrict__ b3f,
    const float* __restrict__ bof,
    const float* __restrict__ optW, const float* __restrict__ optb,
    const float* __restrict__ KW, const float* __restrict__ Kb,
    float* __restrict__ xsim, float* __restrict__ daccs,
    float* __restrict__ Sfin, float* __restrict__ partial)
{
    __shared__ unsigned short hA[16*72];
    __shared__ unsigned short hB[16*72];
    __shared__ unsigned short WtA[64*72];
    __shared__ unsigned short WtB[64*72];
    __shared__ unsigned short WtO[32*72];
    __shared__ float aL[16*20];
    __shared__ float xL[16];
    __shared__ float pacc[48];

    const int tid = threadIdx.x;
    const int rl  = tid >> 4;
    const int la  = tid & 15;
    const int b   = blockIdx.x * 16 + rl;
    const int a2  = 16 + (la & 3);
    const bool act2 = (la < 4);
    const int w2 = tid >> 6;
    const int lw = tid & 63;
    const int cn = lw & 15;
    const int qq = lw >> 4;

    float x = x_in[b];
    const float S00 = S0[b*20 + la];
    const float S01 = S0[b*20 + a2];
    float iS0 = __fdividef(1.f, S00);
    float iS1 = __fdividef(1.f, S01);
    float al0 = fmaf(x, u0W[la], u0b[la]);
    float al1 = act2 ? fmaf(x, u0W[a2], u0b[a2]) : 0.f;
    float Nm10 = al0 * iS0, Nm11 = al1 * iS1;   // seeds n=1 delta to exactly 0
    float dacc0 = 0.f, dacc1 = 0.f;

    const size_t STEP = (size_t)B_TOT * 20;
    const float* pA = dW + (size_t)b*20 + la;
    const float* pB = dW + (size_t)b*20 + a2;

    // phase-0 prefetch: steps 1..10 use dW[0..9]
    float dA[10], dB[10];
#pragma unroll
    for (int s = 0; s < 10; ++s){
        dA[s] = pA[(size_t)s*STEP];
        dB[s] = pB[(size_t)s*STEP];
    }
    const float XA = 1.f + RH;

    for (int p = 0; p < 10; ++p){
        const float su = red16(al0 + al1);
        const float Cp = su * (MUH - RH);
#pragma unroll
        for (int s = 0; s < 10; ++s){
            float np0 = al0 * iS0;
            float np1 = al1 * iS1;
            dacc0 += fabsf(np0 - Nm10);
            dacc1 += fabsf(np1 - Nm11);
            Nm10 = np0; Nm11 = np1;
            float dot = red16(fmaf(al0, dA[s], al1 * dB[s]));
            x = fmaf(SSC, dot, fmaf(x, XA, Cp));
            iS0 *= __expf(fmaf(-SSC, dA[s], -DRIFT));
            iS1 *= __expf(fmaf(-SSC, dB[s], -DRIFT));
        }
        if (p < 9){
            // issue next phase's dW loads NOW — they ride out the MLP section
            {
                const float* qA = pA + (size_t)(p+1)*10*STEP;
                const float* qB = pB + (size_t)(p+1)*10*STEP;
#pragma unroll
                for (int s = 0; s < 10; ++s){
                    dA[s] = qA[(size_t)s*STEP];
                    dB[s] = qB[(size_t)s*STEP];
                }
            }
            if (la == 0) xL[rl] = x;
            __syncthreads();
            {   // stage pre-folded bf16 weights (FULL coverage: 16 u16/thread)
                const unsigned short* W2p = Wc2 + (size_t)p*4096;
                const unsigned short* W3p = Wc3 + (size_t)p*4096;
                const int wr = tid >> 2, sg = (tid & 3) * 16;
                uintx4 v2a = *reinterpret_cast<const uintx4*>(W2p + wr*64 + sg);
                uintx4 v2b = *reinterpret_cast<const uintx4*>(W2p + wr*64 + sg + 8);
                uintx4 v3a = *reinterpret_cast<const uintx4*>(W3p + wr*64 + sg);
                uintx4 v3b = *reinterpret_cast<const uintx4*>(W3p + wr*64 + sg + 8);
                *reinterpret_cast<uintx4*>(&WtA[wr*72 + sg    ]) = v2a;
                *reinterpret_cast<uintx4*>(&WtA[wr*72 + sg + 8]) = v2b;
                *reinterpret_cast<uintx4*>(&WtB[wr*72 + sg    ]) = v3a;
                *reinterpret_cast<uintx4*>(&WtB[wr*72 + sg + 8]) = v3b;
                if (tid < 128){
                    const unsigned short* Wop = Wco + (size_t)p*2048;
                    uintx4 voa = *reinterpret_cast<const uintx4*>(Wop + wr*64 + sg);
                    uintx4 vob = *reinterpret_cast<const uintx4*>(Wop + wr*64 + sg + 8);
                    *reinterpret_cast<uintx4*>(&WtO[wr*72 + sg    ]) = voa;
                    *reinterpret_cast<uintx4*>(&WtO[wr*72 + sg + 8]) = vob;
                }
                const float xr = xL[tid & 15];
                const int u0 = (tid >> 4) * 4;
                const float* Wi = uWin + p*64;
                const float* b0 = ubh + (p*3+0)*64;
                unsigned short h4[4];
#pragma unroll
                for (int i=0;i<4;i++)
                    h4[i] = bfc(fmaxf(fmaf(xr, Wi[u0+i], b0[u0+i]), 0.f));
                uintx2 hw;
                hw.x = (unsigned)h4[0] | ((unsigned)h4[1] << 16);
                hw.y = (unsigned)h4[2] | ((unsigned)h4[3] << 16);
                *reinterpret_cast<uintx2*>(&hA[(tid&15)*72 + u0]) = hw;
            }
            __syncthreads();
            {   // L2: hA x WtA -> hB (relu only; BN folded)
                const int col = 16*w2 + cn;
                float bias = b2f[p*64 + col];
                floatx4 c = {bias, bias, bias, bias};
                short8 a0 = *reinterpret_cast<const short8*>(&hA[cn*72 + qq*8]);
                short8 a1 = *reinterpret_cast<const short8*>(&hA[cn*72 + 32 + qq*8]);
                short8 bb0 = *reinterpret_cast<const short8*>(&WtA[col*72 + qq*8]);
                short8 bb1 = *reinterpret_cast<const short8*>(&WtA[col*72 + 32 + qq*8]);
                c = __builtin_amdgcn_mfma_f32_16x16x32_bf16(a0, bb0, c, 0, 0, 0);
                c = __builtin_amdgcn_mfma_f32_16x16x32_bf16(a1, bb1, c, 0, 0, 0);
#pragma unroll
                for (int i=0;i<4;i++)
                    hB[(qq*4+i)*72 + col] = bfc(fmaxf(c[i], 0.f));
            }
            __syncthreads();
            {   // L3: hB x WtB -> hA
                const int col = 16*w2 + cn;
                float bias = b3f[p*64 + col];
                floatx4 c = {bias, bias, bias, bias};
                short8 a0 = *reinterpret_cast<const short8*>(&hB[cn*72 + qq*8]);
                short8 a1 = *reinterpret_cast<const short8*>(&hB[cn*72 + 32 + qq*8]);
                short8 bb0 = *reinterpret_cast<const short8*>(&WtB[col*72 + qq*8]);
                short8 bb1 = *reinterpret_cast<const short8*>(&WtB[col*72 + 32 + qq*8]);
                c = __builtin_amdgcn_mfma_f32_16x16x32_bf16(a0, bb0, c, 0, 0, 0);
                c = __builtin_amdgcn_mfma_f32_16x16x32_bf16(a1, bb1, c, 0, 0, 0);
#pragma unroll
                for (int i=0;i<4;i++)
                    hA[(qq*4+i)*72 + col] = bfc(fmaxf(c[i], 0.f));
            }
            __syncthreads();
            if (w2 < 2){   // out layer: hA x WtO -> aL
                const int col = 16*w2 + cn;
                float bias = bof[p*32 + col];
                floatx4 c = {bias, bias, bias, bias};
                short8 a0 = *reinterpret_cast<const short8*>(&hA[cn*72 + qq*8]);
                short8 a1 = *reinterpret_cast<const short8*>(&hA[cn*72 + 32 + qq*8]);
                short8 bb0 = *reinterpret_cast<const short8*>(&WtO[col*72 + qq*8]);
                short8 bb1 = *reinterpret_cast<const short8*>(&WtO[col*72 + 32 + qq*8]);
                c = __builtin_amdgcn_mfma_f32_16x16x32_bf16(a0, bb0, c, 0, 0, 0);
                c = __builtin_amdgcn_mfma_f32_16x16x32_bf16(a1, bb1, c, 0, 0, 0);
                if (col < 20){
#pragma unroll
                    for (int i=0;i<4;i++) aL[(qq*4+i)*20 + col] = c[i];
                }
            }
            __syncthreads();
            al0 = aL[rl*20 + la];
            al1 = act2 ? aL[rl*20 + a2] : 0.f;
        }
    }

    // --- per-row outputs ---
    float Sf0 = __fdividef(1.f, iS0);
    float Sf1 = __fdividef(1.f, iS1);
    float ds = red16(dacc0 + dacc1);
    if (la == 0){ xsim[b] = x; daccs[b] = ds; }
    Sfin[b*20 + la] = Sf0;
    if (act2) Sfin[b*20 + a2] = Sf1;

    // --- fused option-head block partials ---
    if (tid < 48) pacc[tid] = 0.f;
    __syncthreads();
    float e1v = __expf(fmaf(x, optW[la],    optb[la]));
    float e2v = __expf(fmaf(x, optW[16+la], optb[16+la]));
    float e3v = (la <= 8) ? __expf(fmaf(x, optW[32+la], optb[32+la])) : 0.f;
    float sAll = red16(e1v + e2v + e3v);
    float e40 = __shfl(e3v, (lw & 48) + 8, 64);
    float afrac = __fdividef(sAll - e40, sAll);
    float kc0 = fmaf(0.25f, tanh_fast(fmaf(x, KW[la],    Kb[la]   )), 1.f);
    float kp0 = fmaf(0.25f, tanh_fast(fmaf(x, KW[20+la], Kb[20+la])), 1.f);
    float sq0 = QF * __fdividef(Sf0, S00);
    atomicAdd(&pacc[la],    fmaxf(sq0 - kc0, 0.f));
    atomicAdd(&pacc[20+la], fmaxf(kp0 - sq0, 0.f));
    if (act2){
        float kc1 = fmaf(0.25f, tanh_fast(fmaf(x, KW[a2],    Kb[a2]   )), 1.f);
        float kp1 = fmaf(0.25f, tanh_fast(fmaf(x, KW[20+a2], Kb[20+a2])), 1.f);
        float sq1 = QF * __fdividef(Sf1, S01);
        atomicAdd(&pacc[a2],    fmaxf(sq1 - kc1, 0.f));
        atomicAdd(&pacc[20+a2], fmaxf(kp1 - sq1, 0.f));
    }
    if (la == 0){
        atomicAdd(&pacc[40], afrac);
        atomicAdd(&pacc[41], fmaxf(Sf0 - kc0, 0.f));
    }
    __syncthreads();
    if (tid < 48) partial[tid*1024 + blockIdx.x] = pacc[tid];
}

// ---------------------------------------------------------------------------
// K2: reduce partials; per-row final wealth; losses 5..7
// ---------------------------------------------------------------------------
__global__ __launch_bounds__(256,1) void k_final(
    const float* __restrict__ x_in,
    const float* __restrict__ optW, const float* __restrict__ optb,
    const float* __restrict__ KW, const float* __restrict__ Kb,
    const float* __restrict__ Sfin, const float* __restrict__ xsim,
    const float* __restrict__ daccs, const float* __restrict__ partial,
    float* __restrict__ xfin, float* __restrict__ out)
{
    __shared__ float accL[48];
    __shared__ float tmp[48][4];
    const int t = threadIdx.x;
    if (t < 192){
        const int r = t >> 2, q = t & 3;
        const floatx4* s4 = (const floatx4*)(partial + r*1024 + q*256);
        float acc = 0.f;
#pragma unroll 4
        for (int i=0;i<64;i++){ floatx4 v = s4[i]; acc += v[0]+v[1]+v[2]+v[3]; }
        tmp[r][q] = acc;
    }
    __syncthreads();
    if (t < 48) accL[t] = tmp[t][0]+tmp[t][1]+tmp[t][2]+tmp[t][3];
    __syncthreads();

    const int b = blockIdx.x*256 + t;
    const float x = x_in[b];
    float e[41]; float m = -1e30f;
#pragma unroll
    for (int k=0;k<41;k++){ e[k] = fmaf(x, optW[k], optb[k]); m = fmaxf(m, e[k]); }
    float s = 0.f;
#pragma unroll
    for (int k=0;k<41;k++){ e[k] = __expf(e[k]-m); s += e[k]; }
    const float invs = 1.f / s;
    const float invB = 1.f / (float)B_TOT;
    const float rescale = 1.f - accL[40]*invB;
    float pay = 0.f, k01 = 0.f;
#pragma unroll
    for (int d=0; d<20; d++){
        float Sv = Sfin[(size_t)b*20 + d];
        float kc = fmaf(0.25f, tanh_fast(fmaf(x, KW[d],    Kb[d]   )), 1.f);
        float kp = fmaf(0.25f, tanh_fast(fmaf(x, KW[20+d], Kb[20+d])), 1.f);
        float C0d = DISC * accL[d]    * invB;
        float P0d = DISC * accL[20+d] * invB;
        pay += (e[d]*invs)    * fmaxf(Sv - kc, 0.f) / C0d;
        pay += (e[20+d]*invs) * fmaxf(kp - Sv, 0.f) / P0d;
        if (d == 1) k01 = kc;
    }
    float xf = rescale * xsim[b] - CURT * rescale * daccs[b] + pay;
    xfin[b] = xf;
    if (b == 0){
        out[4] = accL[41] / (DISC * accL[0]);
        out[5] = k01;
        out[6] = rescale;
    }
}

// ---------------------------------------------------------------------------
// K3: tail — keys in LDS; 3-level (12/10/10) radix select.
// NEW: Hillis-Steele LDS scans (52 barriers) replaced by in-register wave
// scans: L1 = wave 0 (64 bins/lane + shfl_up scan + owner-lane walk),
// L2/L3 = waves 0-3 (one plane each, 16 bins/lane). Integer-exact.
// ---------------------------------------------------------------------------
__global__ __launch_bounds__(1024,1) void k_tail(
    const float* __restrict__ xfin, float* __restrict__ out)
{
    __shared__ unsigned keys[16384];
    __shared__ unsigned hist[4096];
    __shared__ unsigned b1[4], r1[4], b2[4], r2[4];
    __shared__ int rep1[4], rep2[4];
    __shared__ float vals[4];
    __shared__ float pp[2];
    __shared__ double rdd[16][2];
    __shared__ float rff[16][2];
    __shared__ unsigned ruu[16][2];
    const int tid = threadIdx.x;
    const unsigned ranks[4] = {819u, 820u, 15563u, 15564u};

#pragma unroll
    for (int i=0;i<16;i++) keys[tid + i*1024] = toSort(xfin[tid + i*1024]);
#pragma unroll
    for (int i=0;i<4;i++) hist[tid + i*1024] = 0u;
    __syncthreads();

    // ---- Level 1: top 12 bits (wave-aggregated: keys concentrate) ----
#pragma unroll
    for (int i=0;i<16;i++) aggAdd(hist, keys[tid + i*1024] >> 20);
    __syncthreads();
    if (tid < 64){
        const int l = tid;
        unsigned s = 0;
#pragma unroll
        for (int i=0;i<16;i++){
            uintx4 v = *reinterpret_cast<const uintx4*>(&hist[l*64 + i*4]);
            s += v.x + v.y + v.z + v.w;
        }
        unsigned incl = s;
#pragma unroll
        for (int off=1; off<64; off<<=1){
            unsigned t2 = __shfl_up(incl, off, 64);
            if (l >= off) incl += t2;
        }
        const unsigned cumb = incl - s;
#pragma unroll
        for (int t=0;t<4;t++){
            unsigned r = ranks[t];
            if (r >= cumb && r < cumb + s){
                unsigned cum = cumb;
                for (int i=0;i<64;i++){
                    unsigned c = hist[l*64 + i];
                    if (r < cum + c){ b1[t] = (unsigned)(l*64 + i); r1[t] = r - cum; break; }
                    cum += c;
                }
            }
        }
    }
    __syncthreads();
    if (tid == 0){
#pragma unroll
        for (int t=0;t<4;t++)
            rep1[t] = (t>0 && b1[t]==b1[t-1]) ? rep1[t-1] : t;
    }
    __syncthreads();

    // ---- Level 2: bits 19..10 (dedup planes) ----
#pragma unroll
    for (int i=0;i<4;i++) hist[tid + i*1024] = 0u;
    __syncthreads();
#pragma unroll
    for (int i=0;i<16;i++){
        unsigned k = keys[tid + i*1024];
        unsigned h12 = k >> 20, mid = (k >> 10) & 1023u;
#pragma unroll
        for (int t=0;t<4;t++)
            if (rep1[t]==t && h12 == b1[t]) atomicAdd(&hist[t*1024 + (int)mid], 1u);
    }
    __syncthreads();
    if (tid < 256){
        const int p = tid >> 6, l = tid & 63;
        const unsigned* h = hist + rep1[p]*1024;
        unsigned s = 0;
#pragma unroll
        for (int i=0;i<4;i++){
            uintx4 v = *reinterpret_cast<const uintx4*>(&h[l*16 + i*4]);
            s += v.x + v.y + v.z + v.w;
        }
        unsigned incl = s;
#pragma unroll
        for (int off=1; off<64; off<<=1){
            unsigned t2 = __shfl_up(incl, off, 64);
            if (l >= off) incl += t2;
        }
        const unsigned cumb = incl - s;
        unsigned r = r1[p];
        if (r >= cumb && r < cumb + s){
            unsigned cum = cumb;
            for (int i=0;i<16;i++){
                unsigned c = h[l*16 + i];
                if (r < cum + c){ b2[p] = (unsigned)(l*16 + i); r2[p] = r - cum; break; }
                cum += c;
            }
        }
    }
    __syncthreads();
    if (tid == 0){
#pragma unroll
        for (int t=0;t<4;t++)
            rep2[t] = (t>0 && b1[t]==b1[t-1] && b2[t]==b2[t-1]) ? rep2[t-1] : t;
    }
    __syncthreads();

    // ---- Level 3: bits 9..0 ----
#pragma unroll
    for (int i=0;i<4;i++) hist[tid + i*1024] = 0u;
    __syncthreads();
#pragma unroll
    for (int i=0;i<16;i++){
        unsigned k = keys[tid + i*1024];
        unsigned top22 = k >> 10;
#pragma unroll
        for (int t=0;t<4;t++)
            if (rep2[t]==t && top22 == ((b1[t]<<10) | b2[t]))
                atomicAdd(&hist[t*1024 + (int)(k & 1023u)], 1u);
    }
    __syncthreads();
    if (tid < 256){
        const int p = tid >> 6, l = tid & 63;
        const unsigned* h = hist + rep2[p]*1024;
        unsigned s = 0;
#pragma unroll
        for (int i=0;i<4;i++){
            uintx4 v = *reinterpret_cast<const uintx4*>(&h[l*16 + i*4]);
            s += v.x + v.y + v.z + v.w;
        }
        unsigned incl = s;
#pragma unroll
        for (int off=1; off<64; off<<=1){
            unsigned t2 = __shfl_up(incl, off, 64);
            if (l >= off) incl += t2;
        }
        const unsigned cumb = incl - s;
        unsigned r = r2[p];
        if (r >= cumb && r < cumb + s){
            unsigned cum = cumb;
            for (int i=0;i<16;i++){
                unsigned c = h[l*16 + i];
                if (r < cum + c){
                    vals[p] = fromSort((b1[p]<<20) | (b2[p]<<10) | (unsigned)(l*16 + i));
                    break;
                }
                cum += c;
            }
        }
    }
    __syncthreads();
    if (tid == 0){
        pp[0] = vals[0] + 0.15f*(vals[1]-vals[0]);
        pp[1] = vals[2] + 0.85f*(vals[3]-vals[2]);
    }
    __syncthreads();

    // ---- Reductions ----
    const float p5 = pp[0], p95 = pp[1];
    double sv = 0.0, sq = 0.0;
    float lo = 0.f, hi = 0.f;
    unsigned lc = 0u, hc = 0u;
#pragma unroll
    for (int i=0;i<16;i++){
        float v = fromSort(keys[tid + i*1024]);
        sv += (double)v; sq += (double)v*(double)v;
        if (v < p5){ lo += v; lc++; }
        if (v > p95){ hi += v; hc++; }
    }
    for (int o=1;o<64;o<<=1){
        sv += __shfl_xor(sv,o,64);
        sq += __shfl_xor(sq,o,64);
        lo += __shfl_xor(lo,o,64);
        hi += __shfl_xor(hi,o,64);
        lc += __shfl_xor(lc,o,64);
        hc += __shfl_xor(hc,o,64);
    }
    const int wv = tid >> 6, ln = tid & 63;
    if (ln == 0){ rdd[wv][0]=sv; rdd[wv][1]=sq; rff[wv][0]=lo; rff[wv][1]=hi;
                  ruu[wv][0]=lc; ruu[wv][1]=hc; }
    __syncthreads();
    if (tid == 0){
        double a=0, bq=0; float c=0, d=0; unsigned e2=0, f2=0;
        for (int i=0;i<16;i++){ a+=rdd[i][0]; bq+=rdd[i][1]; c+=rff[i][0];
                                 d+=rff[i][1]; e2+=ruu[i][0]; f2+=ruu[i][1]; }
        const double N = (double)B_TOT;
        double mean = a / N;
        out[0] = (float)(-mean);
        out[1] = (float)(bq/N - mean*mean);
        out[2] = -c / (float)(e2 ? e2 : 1u);
        out[3] = -d / (float)(f2 ? f2 : 1u);
    }
}

extern "C" void kernel_launch(void* const* d_in, const int* in_sizes, int n_in,
                              void* d_out, int out_size, void* d_ws, size_t ws_size,
                              hipStream_t stream)
{
    const float* x_in = (const float*)d_in[0];
    const float* S0   = (const float*)d_in[1];
    const float* dW   = (const float*)d_in[2];
    const float* u0W  = (const float*)d_in[3];
    const float* u0b  = (const float*)d_in[4];
    const float* uWin = (const float*)d_in[5];
    const float* uWh  = (const float*)d_in[6];
    const float* ubh  = (const float*)d_in[7];
    const float* bng  = (const float*)d_in[8];
    const float* bnb  = (const float*)d_in[9];
    const float* uWout= (const float*)d_in[10];
    const float* ubout= (const float*)d_in[11];
    const float* optW = (const float*)d_in[12];
    const float* optb = (const float*)d_in[13];
    const float* KW   = (const float*)d_in[14];
    const float* Kb   = (const float*)d_in[15];
    float* out = (float*)d_out;
    float* ws  = (float*)d_ws;

    // float-indexed workspace offsets
    const size_t OFF_XSIM = 0;          // 16384
    const size_t OFF_DACC = 16384;      // 16384
    const size_t OFF_S    = 32768;      // 327680
    const size_t OFF_XFIN = 360448;     // 16384
    const size_t OFF_PART = 376832;     // 48*1024
    const size_t OFF_WC2  = 425984;     // 10*64*64 bf16 = 20480 floats
    const size_t OFF_WC3  = 446464;     // 20480
    const size_t OFF_WCO  = 466944;     // 10*32*64 bf16 = 10240 floats
    const size_t OFF_B2F  = 477184;     // 640
    const size_t OFF_B3F  = 477824;     // 640
    const size_t OFF_BOF  = 478464;     // 320

    unsigned short* Wc2 = (unsigned short*)(ws + OFF_WC2);
    unsigned short* Wc3 = (unsigned short*)(ws + OFF_WC3);
    unsigned short* Wco = (unsigned short*)(ws + OFF_WCO);

    k_conv<<<30,256,0,stream>>>(uWh, ubh, bng, bnb, uWout, ubout,
                                Wc2, Wc3, Wco,
                                ws+OFF_B2F, ws+OFF_B3F, ws+OFF_BOF);
    k_sim<<<1024,256,0,stream>>>(x_in, S0, dW, u0W, u0b, uWin, ubh,
                                 Wc2, Wc3, Wco,
                                 ws+OFF_B2F, ws+OFF_B3F, ws+OFF_BOF,
                                 optW, optb, KW, Kb,
                                 ws+OFF_XSIM, ws+OFF_DACC, ws+OFF_S, ws+OFF_PART);
    k_final<<<64,256,0,stream>>>(x_in, optW, optb, KW, Kb,
                                 ws+OFF_S, ws+OFF_XSIM, ws+OFF_DACC, ws+OFF_PART,
                                 ws+OFF_XFIN, out);
    k_tail<<<1,1024,0,stream>>>(ws+OFF_XFIN, out);
}

// Round 3
// 304.212 us; speedup vs baseline: 1.0468x; 1.0468x over previous
//
#include <hip/hip_runtime.h>
#include <cstdint>
#include <cstddef>

#define B_TOT 16384
#define NSTEP 100

#define SQRT_H 0.1f
#define RH     2.0e-4f                 // R*h
#define MUH    6.0e-4f                 // MU*h
#define DRIFT  4.0e-4f                 // (MU - 0.5*SIG^2)*h
#define SIGC   0.2f
#define SSC    0.02f                   // SIGC*SQRT_H
#define INVBN  0.99950037468877324f    // 1/sqrt(1+1e-3)
#define QF     0.96078943915232318f    // exp(100*(R-MU)*h)
#define DISC   0.98019867330675525f    // exp(-R*T)
#define CURT   0.005f

typedef __attribute__((ext_vector_type(8))) short short8;
typedef __attribute__((ext_vector_type(4))) float floatx4;
typedef __attribute__((ext_vector_type(4))) unsigned uintx4;
typedef __attribute__((ext_vector_type(2))) unsigned uintx2;

__device__ __forceinline__ unsigned toSort(float f){
    unsigned u = __float_as_uint(f);
    return (u & 0x80000000u) ? ~u : (u | 0x80000000u);
}
__device__ __forceinline__ float fromSort(unsigned s){
    unsigned u = (s & 0x80000000u) ? (s & 0x7fffffffu) : ~s;
    return __uint_as_float(u);
}
__device__ __forceinline__ unsigned short bfc(float f){   // f32->bf16 RNE
    unsigned u = __float_as_uint(f);
    unsigned r = u + 0x7FFFu + ((u >> 16) & 1u);
    return (unsigned short)(r >> 16);
}
__device__ __forceinline__ float red16(float v){
    float t;
    t = __int_as_float(__builtin_amdgcn_update_dpp(0, __float_as_int(v), 0x128, 0xF, 0xF, false)); v += t;
    t = __int_as_float(__builtin_amdgcn_update_dpp(0, __float_as_int(v), 0x124, 0xF, 0xF, false)); v += t;
    t = __int_as_float(__builtin_amdgcn_update_dpp(0, __float_as_int(v), 0x122, 0xF, 0xF, false)); v += t;
    t = __int_as_float(__builtin_amdgcn_update_dpp(0, __float_as_int(v), 0x121, 0xF, 0xF, false)); v += t;
    return v;
}
__device__ __forceinline__ float tanh_fast(float z){
    z = fminf(9.f, fmaxf(-9.f, z));
    float e = __expf(2.f * z);
    return __fdividef(e - 1.f, e + 1.f);
}
__device__ __forceinline__ unsigned laneid(){
    return __builtin_amdgcn_mbcnt_hi(~0u, __builtin_amdgcn_mbcnt_lo(~0u, 0u));
}
// wave-aggregated LDS histogram add (handles heavy same-bin concentration)
__device__ __forceinline__ void aggAdd(unsigned* hist, unsigned bin){
    bool pending = true;
    unsigned lid = laneid();
    while (__any(pending)){
        if (pending){
            unsigned lead = (unsigned)__builtin_amdgcn_readfirstlane((int)bin);
            if (bin == lead){
                unsigned long long m = __ballot(1);
                if (lid == (unsigned)__builtin_ctzll(m))
                    atomicAdd(&hist[lead], (unsigned)__popcll(m));
                pending = false;
            }
        }
    }
}
// exclusive wave scan of unsigned (width 64); returns exclusive prefix,
// and writes the inclusive total of lane 63 via shfl by caller if needed
__device__ __forceinline__ unsigned wexscan(unsigned s, int l){
    unsigned incl = s;
#pragma unroll
    for (int off=1; off<64; off<<=1){
        unsigned t2 = __shfl_up(incl, off, 64);
        if (l >= off) incl += t2;
    }
    return incl - s;
}

// ---------------------------------------------------------------------------
// K0: fold BN scale/shift into weights, pre-convert to bf16.
// W2'[k][j]=W2[k][j]*g0[k]; b2'[j]=b2[j]+sum_k W2[k][j]*beta0[k]; etc.
// Layouts: Wc2/Wc3 [p][j][k] (j=out unit, k contig 64), Wco [p][d(pad32)][k].
// ---------------------------------------------------------------------------
__global__ __launch_bounds__(256,1) void k_conv(
    const float* __restrict__ uWh, const float* __restrict__ ubh,
    const float* __restrict__ bng, const float* __restrict__ bnb,
    const float* __restrict__ uWout, const float* __restrict__ ubout,
    unsigned short* __restrict__ Wc2, unsigned short* __restrict__ Wc3,
    unsigned short* __restrict__ Wco,
    float* __restrict__ b2f, float* __restrict__ b3f, float* __restrict__ bof)
{
    const int p = blockIdx.x;
    const int t = threadIdx.x;
    __shared__ float g0s[64], g1s[64], g2s[64], e0s[64], e1s[64], e2s[64];
    __shared__ float red4[64][4];
    __shared__ float red8[32][8];
    if (t < 64){
        g0s[t] = INVBN * bng[(p*3+0)*64 + t]; e0s[t] = bnb[(p*3+0)*64 + t];
        g1s[t] = INVBN * bng[(p*3+1)*64 + t]; e1s[t] = bnb[(p*3+1)*64 + t];
        g2s[t] = INVBN * bng[(p*3+2)*64 + t]; e2s[t] = bnb[(p*3+2)*64 + t];
    }
    __syncthreads();
    {
        const int j = t & 63, kq = t >> 6;
        float bs = 0.f;
        for (int k = kq*16; k < kq*16+16; ++k){
            float w = uWh[((size_t)(p*2+0)*64 + k)*64 + j];
            bs += w * e0s[k];
            Wc2[(size_t)(p*64 + j)*64 + k] = bfc(w * g0s[k]);
        }
        red4[j][kq] = bs;
    }
    __syncthreads();
    if (t < 64) b2f[p*64 + t] = ubh[(p*3+1)*64 + t]
                 + red4[t][0]+red4[t][1]+red4[t][2]+red4[t][3];
    __syncthreads();
    {
        const int j = t & 63, kq = t >> 6;
        float bs = 0.f;
        for (int k = kq*16; k < kq*16+16; ++k){
            float w = uWh[((size_t)(p*2+1)*64 + k)*64 + j];
            bs += w * e1s[k];
            Wc3[(size_t)(p*64 + j)*64 + k] = bfc(w * g1s[k]);
        }
        red4[j][kq] = bs;
    }
    __syncthreads();
    if (t < 64) b3f[p*64 + t] = ubh[(p*3+2)*64 + t]
                 + red4[t][0]+red4[t][1]+red4[t][2]+red4[t][3];
    __syncthreads();
    {
        const int d = t & 31, kq = t >> 5;
        float bs = 0.f;
        for (int k = kq*8; k < kq*8+8; ++k){
            float w = (d < 20) ? uWout[((size_t)p*64 + k)*20 + d] : 0.f;
            bs += w * e2s[k];
            Wco[(size_t)(p*32 + d)*64 + k] = bfc(w * g2s[k]);
        }
        red8[d][kq] = bs;
    }
    __syncthreads();
    if (t < 32){
        float s = 0.f;
        for (int q=0;q<8;q++) s += red8[t][q];
        bof[p*32 + t] = ((t < 20) ? ubout[p*20 + t] : 0.f) + s;
    }
}

// ---------------------------------------------------------------------------
// K1: SDE scan + fused option-head partial reduction.
// 16 lanes/row; phase-invariant sum(u) hoisted; invS tracking (no divides);
// MLP via bf16 MFMA on pre-folded weights; phase-batched dW register
// prefetch (loads for phase p+1 issue before the MLP barriers).
// ---------------------------------------------------------------------------
__global__ __launch_bounds__(256, 4) void k_sim(
    const float* __restrict__ x_in, const float* __restrict__ S0,
    const float* __restrict__ dW,
    const float* __restrict__ u0W, const float* __restrict__ u0b,
    const float* __restrict__ uWin, const float* __restrict__ ubh,
    const unsigned short* __restrict__ Wc2, const unsigned short* __restrict__ Wc3,
    const unsigned short* __restrict__ Wco,
    const float* __restrict__ b2f, const float* __restrict__ b3f,
    const float* __restrict__ bof,
    const float* __restrict__ optW, const float* __restrict__ optb,
    const float* __restrict__ KW, const float* __restrict__ Kb,
    float* __restrict__ xsim, float* __restrict__ daccs,
    float* __restrict__ Sfin, float* __restrict__ partial)
{
    __shared__ unsigned short hA[16*72];
    __shared__ unsigned short hB[16*72];
    __shared__ unsigned short WtA[64*72];
    __shared__ unsigned short WtB[64*72];
    __shared__ unsigned short WtO[32*72];
    __shared__ float aL[16*20];
    __shared__ float xL[16];
    __shared__ float pacc[48];

    const int tid = threadIdx.x;
    const int rl  = tid >> 4;
    const int la  = tid & 15;
    const int b   = blockIdx.x * 16 + rl;
    const int a2  = 16 + (la & 3);
    const bool act2 = (la < 4);
    const int w2 = tid >> 6;
    const int lw = tid & 63;
    const int cn = lw & 15;
    const int qq = lw >> 4;

    float x = x_in[b];
    const float S00 = S0[b*20 + la];
    const float S01 = S0[b*20 + a2];
    float iS0 = __fdividef(1.f, S00);
    float iS1 = __fdividef(1.f, S01);
    float al0 = fmaf(x, u0W[la], u0b[la]);
    float al1 = act2 ? fmaf(x, u0W[a2], u0b[a2]) : 0.f;
    float Nm10 = al0 * iS0, Nm11 = al1 * iS1;   // seeds n=1 delta to exactly 0
    float dacc0 = 0.f, dacc1 = 0.f;

    const size_t STEP = (size_t)B_TOT * 20;
    const float* pA = dW + (size_t)b*20 + la;
    const float* pB = dW + (size_t)b*20 + a2;

    // phase-0 prefetch: steps 1..10 use dW[0..9]
    float dA[10], dB[10];
#pragma unroll
    for (int s = 0; s < 10; ++s){
        dA[s] = pA[(size_t)s*STEP];
        dB[s] = pB[(size_t)s*STEP];
    }
    const float XA = 1.f + RH;

    for (int p = 0; p < 10; ++p){
        const float su = red16(al0 + al1);
        const float Cp = su * (MUH - RH);
#pragma unroll
        for (int s = 0; s < 10; ++s){
            float np0 = al0 * iS0;
            float np1 = al1 * iS1;
            dacc0 += fabsf(np0 - Nm10);
            dacc1 += fabsf(np1 - Nm11);
            Nm10 = np0; Nm11 = np1;
            float dot = red16(fmaf(al0, dA[s], al1 * dB[s]));
            x = fmaf(SSC, dot, fmaf(x, XA, Cp));
            iS0 *= __expf(fmaf(-SSC, dA[s], -DRIFT));
            iS1 *= __expf(fmaf(-SSC, dB[s], -DRIFT));
        }
        if (p < 9){
            // issue next phase's dW loads NOW — they ride out the MLP section
            {
                const float* qA = pA + (size_t)(p+1)*10*STEP;
                const float* qB = pB + (size_t)(p+1)*10*STEP;
#pragma unroll
                for (int s = 0; s < 10; ++s){
                    dA[s] = qA[(size_t)s*STEP];
                    dB[s] = qB[(size_t)s*STEP];
                }
            }
            if (la == 0) xL[rl] = x;
            __syncthreads();
            {   // stage pre-folded bf16 weights (FULL coverage: 16 u16/thread)
                const unsigned short* W2p = Wc2 + (size_t)p*4096;
                const unsigned short* W3p = Wc3 + (size_t)p*4096;
                const int wr = tid >> 2, sg = (tid & 3) * 16;
                uintx4 v2a = *reinterpret_cast<const uintx4*>(W2p + wr*64 + sg);
                uintx4 v2b = *reinterpret_cast<const uintx4*>(W2p + wr*64 + sg + 8);
                uintx4 v3a = *reinterpret_cast<const uintx4*>(W3p + wr*64 + sg);
                uintx4 v3b = *reinterpret_cast<const uintx4*>(W3p + wr*64 + sg + 8);
                *reinterpret_cast<uintx4*>(&WtA[wr*72 + sg    ]) = v2a;
                *reinterpret_cast<uintx4*>(&WtA[wr*72 + sg + 8]) = v2b;
                *reinterpret_cast<uintx4*>(&WtB[wr*72 + sg    ]) = v3a;
                *reinterpret_cast<uintx4*>(&WtB[wr*72 + sg + 8]) = v3b;
                if (tid < 128){
                    const unsigned short* Wop = Wco + (size_t)p*2048;
                    uintx4 voa = *reinterpret_cast<const uintx4*>(Wop + wr*64 + sg);
                    uintx4 vob = *reinterpret_cast<const uintx4*>(Wop + wr*64 + sg + 8);
                    *reinterpret_cast<uintx4*>(&WtO[wr*72 + sg    ]) = voa;
                    *reinterpret_cast<uintx4*>(&WtO[wr*72 + sg + 8]) = vob;
                }
                const float xr = xL[tid & 15];
                const int u0 = (tid >> 4) * 4;
                const float* Wi = uWin + p*64;
                const float* b0 = ubh + (p*3+0)*64;
                unsigned short h4[4];
#pragma unroll
                for (int i=0;i<4;i++)
                    h4[i] = bfc(fmaxf(fmaf(xr, Wi[u0+i], b0[u0+i]), 0.f));
                uintx2 hw;
                hw.x = (unsigned)h4[0] | ((unsigned)h4[1] << 16);
                hw.y = (unsigned)h4[2] | ((unsigned)h4[3] << 16);
                *reinterpret_cast<uintx2*>(&hA[(tid&15)*72 + u0]) = hw;
            }
            __syncthreads();
            {   // L2: hA x WtA -> hB (relu only; BN folded)
                const int col = 16*w2 + cn;
                float bias = b2f[p*64 + col];
                floatx4 c = {bias, bias, bias, bias};
                short8 a0 = *reinterpret_cast<const short8*>(&hA[cn*72 + qq*8]);
                short8 a1 = *reinterpret_cast<const short8*>(&hA[cn*72 + 32 + qq*8]);
                short8 bb0 = *reinterpret_cast<const short8*>(&WtA[col*72 + qq*8]);
                short8 bb1 = *reinterpret_cast<const short8*>(&WtA[col*72 + 32 + qq*8]);
                c = __builtin_amdgcn_mfma_f32_16x16x32_bf16(a0, bb0, c, 0, 0, 0);
                c = __builtin_amdgcn_mfma_f32_16x16x32_bf16(a1, bb1, c, 0, 0, 0);
#pragma unroll
                for (int i=0;i<4;i++)
                    hB[(qq*4+i)*72 + col] = bfc(fmaxf(c[i], 0.f));
            }
            __syncthreads();
            {   // L3: hB x WtB -> hA
                const int col = 16*w2 + cn;
                float bias = b3f[p*64 + col];
                floatx4 c = {bias, bias, bias, bias};
                short8 a0 = *reinterpret_cast<const short8*>(&hB[cn*72 + qq*8]);
                short8 a1 = *reinterpret_cast<const short8*>(&hB[cn*72 + 32 + qq*8]);
                short8 bb0 = *reinterpret_cast<const short8*>(&WtB[col*72 + qq*8]);
                short8 bb1 = *reinterpret_cast<const short8*>(&WtB[col*72 + 32 + qq*8]);
                c = __builtin_amdgcn_mfma_f32_16x16x32_bf16(a0, bb0, c, 0, 0, 0);
                c = __builtin_amdgcn_mfma_f32_16x16x32_bf16(a1, bb1, c, 0, 0, 0);
#pragma unroll
                for (int i=0;i<4;i++)
                    hA[(qq*4+i)*72 + col] = bfc(fmaxf(c[i], 0.f));
            }
            __syncthreads();
            if (w2 < 2){   // out layer: hA x WtO -> aL
                const int col = 16*w2 + cn;
                float bias = bof[p*32 + col];
                floatx4 c = {bias, bias, bias, bias};
                short8 a0 = *reinterpret_cast<const short8*>(&hA[cn*72 + qq*8]);
                short8 a1 = *reinterpret_cast<const short8*>(&hA[cn*72 + 32 + qq*8]);
                short8 bb0 = *reinterpret_cast<const short8*>(&WtO[col*72 + qq*8]);
                short8 bb1 = *reinterpret_cast<const short8*>(&WtO[col*72 + 32 + qq*8]);
                c = __builtin_amdgcn_mfma_f32_16x16x32_bf16(a0, bb0, c, 0, 0, 0);
                c = __builtin_amdgcn_mfma_f32_16x16x32_bf16(a1, bb1, c, 0, 0, 0);
                if (col < 20){
#pragma unroll
                    for (int i=0;i<4;i++) aL[(qq*4+i)*20 + col] = c[i];
                }
            }
            __syncthreads();
            al0 = aL[rl*20 + la];
            al1 = act2 ? aL[rl*20 + a2] : 0.f;
        }
    }

    // --- per-row outputs ---
    float Sf0 = __fdividef(1.f, iS0);
    float Sf1 = __fdividef(1.f, iS1);
    float ds = red16(dacc0 + dacc1);
    if (la == 0){ xsim[b] = x; daccs[b] = ds; }
    Sfin[b*20 + la] = Sf0;
    if (act2) Sfin[b*20 + a2] = Sf1;

    // --- fused option-head block partials ---
    if (tid < 48) pacc[tid] = 0.f;
    __syncthreads();
    float e1v = __expf(fmaf(x, optW[la],    optb[la]));
    float e2v = __expf(fmaf(x, optW[16+la], optb[16+la]));
    float e3v = (la <= 8) ? __expf(fmaf(x, optW[32+la], optb[32+la])) : 0.f;
    float sAll = red16(e1v + e2v + e3v);
    float e40 = __shfl(e3v, (lw & 48) + 8, 64);
    float afrac = __fdividef(sAll - e40, sAll);
    float kc0 = fmaf(0.25f, tanh_fast(fmaf(x, KW[la],    Kb[la]   )), 1.f);
    float kp0 = fmaf(0.25f, tanh_fast(fmaf(x, KW[20+la], Kb[20+la])), 1.f);
    float sq0 = QF * __fdividef(Sf0, S00);
    atomicAdd(&pacc[la],    fmaxf(sq0 - kc0, 0.f));
    atomicAdd(&pacc[20+la], fmaxf(kp0 - sq0, 0.f));
    if (act2){
        float kc1 = fmaf(0.25f, tanh_fast(fmaf(x, KW[a2],    Kb[a2]   )), 1.f);
        float kp1 = fmaf(0.25f, tanh_fast(fmaf(x, KW[20+a2], Kb[20+a2])), 1.f);
        float sq1 = QF * __fdividef(Sf1, S01);
        atomicAdd(&pacc[a2],    fmaxf(sq1 - kc1, 0.f));
        atomicAdd(&pacc[20+a2], fmaxf(kp1 - sq1, 0.f));
    }
    if (la == 0){
        atomicAdd(&pacc[40], afrac);
        atomicAdd(&pacc[41], fmaxf(Sf0 - kc0, 0.f));
    }
    __syncthreads();
    if (tid < 48) partial[tid*1024 + blockIdx.x] = pacc[tid];
}

// ---------------------------------------------------------------------------
// K2: reduce partials; per-row final wealth; losses 5..7
// ---------------------------------------------------------------------------
__global__ __launch_bounds__(256,1) void k_final(
    const float* __restrict__ x_in,
    const float* __restrict__ optW, const float* __restrict__ optb,
    const float* __restrict__ KW, const float* __restrict__ Kb,
    const float* __restrict__ Sfin, const float* __restrict__ xsim,
    const float* __restrict__ daccs, const float* __restrict__ partial,
    float* __restrict__ xfin, float* __restrict__ out)
{
    __shared__ float accL[48];
    __shared__ float tmp[48][4];
    const int t = threadIdx.x;
    if (t < 192){
        const int r = t >> 2, q = t & 3;
        const floatx4* s4 = (const floatx4*)(partial + r*1024 + q*256);
        float acc = 0.f;
#pragma unroll 4
        for (int i=0;i<64;i++){ floatx4 v = s4[i]; acc += v[0]+v[1]+v[2]+v[3]; }
        tmp[r][q] = acc;
    }
    __syncthreads();
    if (t < 48) accL[t] = tmp[t][0]+tmp[t][1]+tmp[t][2]+tmp[t][3];
    __syncthreads();

    const int b = blockIdx.x*256 + t;
    const float x = x_in[b];
    float e[41]; float m = -1e30f;
#pragma unroll
    for (int k=0;k<41;k++){ e[k] = fmaf(x, optW[k], optb[k]); m = fmaxf(m, e[k]); }
    float s = 0.f;
#pragma unroll
    for (int k=0;k<41;k++){ e[k] = __expf(e[k]-m); s += e[k]; }
    const float invs = 1.f / s;
    const float invB = 1.f / (float)B_TOT;
    const float rescale = 1.f - accL[40]*invB;
    float pay = 0.f, k01 = 0.f;
#pragma unroll
    for (int d=0; d<20; d++){
        float Sv = Sfin[(size_t)b*20 + d];
        float kc = fmaf(0.25f, tanh_fast(fmaf(x, KW[d],    Kb[d]   )), 1.f);
        float kp = fmaf(0.25f, tanh_fast(fmaf(x, KW[20+d], Kb[20+d])), 1.f);
        float C0d = DISC * accL[d]    * invB;
        float P0d = DISC * accL[20+d] * invB;
        pay += (e[d]*invs)    * fmaxf(Sv - kc, 0.f) / C0d;
        pay += (e[20+d]*invs) * fmaxf(kp - Sv, 0.f) / P0d;
        if (d == 1) k01 = kc;
    }
    float xf = rescale * xsim[b] - CURT * rescale * daccs[b] + pay;
    xfin[b] = xf;
    if (b == 0){
        out[4] = accL[41] / (DISC * accL[0]);
        out[5] = k01;
        out[6] = rescale;
    }
}

// ---------------------------------------------------------------------------
// K3: tail — keys in LDS; 3-level (12/10/10) radix select.
// Scan/select phases are single-wave, fully parallel:
//   per-lane group sums (lane-rotated chunk order -> 4-way not 64-way bank
//   conflicts), shfl_up wave scan, ballot+ctz owner find, one shfl
//   broadcast, then ALL lanes cooperatively resolve the bin with a second
//   wave scan + ballot. No serial walks, no block-wide scan barriers.
// Integer-exact vs the Hillis-Steele version.
// ---------------------------------------------------------------------------
__global__ __launch_bounds__(1024,1) void k_tail(
    const float* __restrict__ xfin, float* __restrict__ out)
{
    __shared__ unsigned keys[16384];
    __shared__ unsigned hist[4096];
    __shared__ unsigned b1[4], r1[4], b2[4], r2[4];
    __shared__ int rep1[4], rep2[4];
    __shared__ float vals[4];
    __shared__ float pp[2];
    __shared__ double rdd[16][2];
    __shared__ float rff[16][2];
    __shared__ unsigned ruu[16][2];
    const int tid = threadIdx.x;
    const unsigned ranks[4] = {819u, 820u, 15563u, 15564u};

#pragma unroll
    for (int i=0;i<16;i++) keys[tid + i*1024] = toSort(xfin[tid + i*1024]);
#pragma unroll
    for (int i=0;i<4;i++) hist[tid + i*1024] = 0u;
    __syncthreads();

    // ---- Level 1: top 12 bits (wave-aggregated: keys concentrate) ----
#pragma unroll
    for (int i=0;i<16;i++) aggAdd(hist, keys[tid + i*1024] >> 20);
    __syncthreads();
    if (tid < 64){
        const int l = tid;
        // per-lane sum of 64-bin group, lane-rotated chunk order
        unsigned s = 0;
#pragma unroll
        for (int i=0;i<16;i++){
            const int j = (i + l) & 15;
            uintx4 v = *reinterpret_cast<const uintx4*>(&hist[l*64 + j*4]);
            s += v.x + v.y + v.z + v.w;
        }
        const unsigned cumb = wexscan(s, l);
#pragma unroll
        for (int t=0;t<4;t++){
            const unsigned r = ranks[t];
            bool own = (r >= cumb) && (r < cumb + s);
            unsigned long long m = __ballot(own);
            int owner = (int)__builtin_ctzll(m);
            unsigned cb = (unsigned)__shfl((int)cumb, owner, 64);
            unsigned rr = r - cb;
            // all 64 lanes resolve the bin inside group `owner`
            unsigned c = hist[owner*64 + l];
            unsigned cex = wexscan(c, l);
            if (rr >= cex && rr < cex + c){
                b1[t] = (unsigned)(owner*64 + l);
                r1[t] = rr - cex;
            }
        }
    }
    __syncthreads();
    if (tid == 0){
#pragma unroll
        for (int t=0;t<4;t++)
            rep1[t] = (t>0 && b1[t]==b1[t-1]) ? rep1[t-1] : t;
    }
    __syncthreads();

    // ---- Level 2: bits 19..10 (dedup planes) ----
#pragma unroll
    for (int i=0;i<4;i++) hist[tid + i*1024] = 0u;
    __syncthreads();
#pragma unroll
    for (int i=0;i<16;i++){
        unsigned k = keys[tid + i*1024];
        unsigned h12 = k >> 20, mid = (k >> 10) & 1023u;
#pragma unroll
        for (int t=0;t<4;t++)
            if (rep1[t]==t && h12 == b1[t]) atomicAdd(&hist[t*1024 + (int)mid], 1u);
    }
    __syncthreads();
    if (tid < 256){
        const int p = tid >> 6, l = tid & 63;
        const unsigned* h = hist + rep1[p]*1024;
        unsigned s = 0;
#pragma unroll
        for (int i=0;i<4;i++){
            const int j = (i + l) & 3;
            uintx4 v = *reinterpret_cast<const uintx4*>(&h[l*16 + j*4]);
            s += v.x + v.y + v.z + v.w;
        }
        const unsigned cumb = wexscan(s, l);
        const unsigned r = r1[p];
        bool own = (r >= cumb) && (r < cumb + s);
        unsigned long long m = __ballot(own);
        int owner = (int)__builtin_ctzll(m);
        unsigned cb = (unsigned)__shfl((int)cumb, owner, 64);
        unsigned rr = r - cb;
        unsigned c = (l < 16) ? h[owner*16 + l] : 0u;
        unsigned cex = wexscan(c, l);
        if (l < 16 && rr >= cex && rr < cex + c){
            b2[p] = (unsigned)(owner*16 + l);
            r2[p] = rr - cex;
        }
    }
    __syncthreads();
    if (tid == 0){
#pragma unroll
        for (int t=0;t<4;t++)
            rep2[t] = (t>0 && b1[t]==b1[t-1] && b2[t]==b2[t-1]) ? rep2[t-1] : t;
    }
    __syncthreads();

    // ---- Level 3: bits 9..0 ----
#pragma unroll
    for (int i=0;i<4;i++) hist[tid + i*1024] = 0u;
    __syncthreads();
#pragma unroll
    for (int i=0;i<16;i++){
        unsigned k = keys[tid + i*1024];
        unsigned top22 = k >> 10;
#pragma unroll
        for (int t=0;t<4;t++)
            if (rep2[t]==t && top22 == ((b1[t]<<10) | b2[t]))
                atomicAdd(&hist[t*1024 + (int)(k & 1023u)], 1u);
    }
    __syncthreads();
    if (tid < 256){
        const int p = tid >> 6, l = tid & 63;
        const unsigned* h = hist + rep2[p]*1024;
        unsigned s = 0;
#pragma unroll
        for (int i=0;i<4;i++){
            const int j = (i + l) & 3;
            uintx4 v = *reinterpret_cast<const uintx4*>(&h[l*16 + j*4]);
            s += v.x + v.y + v.z + v.w;
        }
        const unsigned cumb = wexscan(s, l);
        const unsigned r = r2[p];
        bool own = (r >= cumb) && (r < cumb + s);
        unsigned long long m = __ballot(own);
        int owner = (int)__builtin_ctzll(m);
        unsigned cb = (unsigned)__shfl((int)cumb, owner, 64);
        unsigned rr = r - cb;
        unsigned c = (l < 16) ? h[owner*16 + l] : 0u;
        unsigned cex = wexscan(c, l);
        if (l < 16 && rr >= cex && rr < cex + c){
            vals[p] = fromSort((b1[p]<<20) | (b2[p]<<10) | (unsigned)(owner*16 + l));
        }
    }
    __syncthreads();
    if (tid == 0){
        pp[0] = vals[0] + 0.15f*(vals[1]-vals[0]);
        pp[1] = vals[2] + 0.85f*(vals[3]-vals[2]);
    }
    __syncthreads();

    // ---- Reductions ----
    const float p5 = pp[0], p95 = pp[1];
    double sv = 0.0, sq = 0.0;
    float lo = 0.f, hi = 0.f;
    unsigned lc = 0u, hc = 0u;
#pragma unroll
    for (int i=0;i<16;i++){
        float v = fromSort(keys[tid + i*1024]);
        sv += (double)v; sq += (double)v*(double)v;
        if (v < p5){ lo += v; lc++; }
        if (v > p95){ hi += v; hc++; }
    }
    for (int o=1;o<64;o<<=1){
        sv += __shfl_xor(sv,o,64);
        sq += __shfl_xor(sq,o,64);
        lo += __shfl_xor(lo,o,64);
        hi += __shfl_xor(hi,o,64);
        lc += __shfl_xor(lc,o,64);
        hc += __shfl_xor(hc,o,64);
    }
    const int wv = tid >> 6, ln = tid & 63;
    if (ln == 0){ rdd[wv][0]=sv; rdd[wv][1]=sq; rff[wv][0]=lo; rff[wv][1]=hi;
                  ruu[wv][0]=lc; ruu[wv][1]=hc; }
    __syncthreads();
    if (tid == 0){
        double a=0, bq=0; float c=0, d=0; unsigned e2=0, f2=0;
        for (int i=0;i<16;i++){ a+=rdd[i][0]; bq+=rdd[i][1]; c+=rff[i][0];
                                 d+=rff[i][1]; e2+=ruu[i][0]; f2+=ruu[i][1]; }
        const double N = (double)B_TOT;
        double mean = a / N;
        out[0] = (float)(-mean);
        out[1] = (float)(bq/N - mean*mean);
        out[2] = -c / (float)(e2 ? e2 : 1u);
        out[3] = -d / (float)(f2 ? f2 : 1u);
    }
}

extern "C" void kernel_launch(void* const* d_in, const int* in_sizes, int n_in,
                              void* d_out, int out_size, void* d_ws, size_t ws_size,
                              hipStream_t stream)
{
    const float* x_in = (const float*)d_in[0];
    const float* S0   = (const float*)d_in[1];
    const float* dW   = (const float*)d_in[2];
    const float* u0W  = (const float*)d_in[3];
    const float* u0b  = (const float*)d_in[4];
    const float* uWin = (const float*)d_in[5];
    const float* uWh  = (const float*)d_in[6];
    const float* ubh  = (const float*)d_in[7];
    const float* bng  = (const float*)d_in[8];
    const float* bnb  = (const float*)d_in[9];
    const float* uWout= (const float*)d_in[10];
    const float* ubout= (const float*)d_in[11];
    const float* optW = (const float*)d_in[12];
    const float* optb = (const float*)d_in[13];
    const float* KW   = (const float*)d_in[14];
    const float* Kb   = (const float*)d_in[15];
    float* out = (float*)d_out;
    float* ws  = (float*)d_ws;

    // float-indexed workspace offsets
    const size_t OFF_XSIM = 0;          // 16384
    const size_t OFF_DACC = 16384;      // 16384
    const size_t OFF_S    = 32768;      // 327680
    const size_t OFF_XFIN = 360448;     // 16384
    const size_t OFF_PART = 376832;     // 48*1024
    const size_t OFF_WC2  = 425984;     // 10*64*64 bf16 = 20480 floats
    const size_t OFF_WC3  = 446464;     // 20480
    const size_t OFF_WCO  = 466944;     // 10*32*64 bf16 = 10240 floats
    const size_t OFF_B2F  = 477184;     // 640
    const size_t OFF_B3F  = 477824;     // 640
    const size_t OFF_BOF  = 478464;     // 320

    unsigned short* Wc2 = (unsigned short*)(ws + OFF_WC2);
    unsigned short* Wc3 = (unsigned short*)(ws + OFF_WC3);
    unsigned short* Wco = (unsigned short*)(ws + OFF_WCO);

    k_conv<<<10,256,0,stream>>>(uWh, ubh, bng, bnb, uWout, ubout,
                                Wc2, Wc3, Wco,
                                ws+OFF_B2F, ws+OFF_B3F, ws+OFF_BOF);
    k_sim<<<1024,256,0,stream>>>(x_in, S0, dW, u0W, u0b, uWin, ubh,
                                 Wc2, Wc3, Wco,
                                 ws+OFF_B2F, ws+OFF_B3F, ws+OFF_BOF,
                                 optW, optb, KW, Kb,
                                 ws+OFF_XSIM, ws+OFF_DACC, ws+OFF_S, ws+OFF_PART);
    k_final<<<64,256,0,stream>>>(x_in, optW, optb, KW, Kb,
                                 ws+OFF_S, ws+OFF_XSIM, ws+OFF_DACC, ws+OFF_PART,
                                 ws+OFF_XFIN, out);
    k_tail<<<1,1024,0,stream>>>(ws+OFF_XFIN, out);
}

// Round 4
// 301.890 us; speedup vs baseline: 1.0548x; 1.0077x over previous
//
#include <hip/hip_runtime.h>
#include <cstdint>
#include <cstddef>

#define B_TOT 16384
#define NSTEP 100

#define SQRT_H 0.1f
#define RH     2.0e-4f                 // R*h
#define MUH    6.0e-4f                 // MU*h
#define DRIFT  4.0e-4f                 // (MU - 0.5*SIG^2)*h
#define SIGC   0.2f
#define SSC    0.02f                   // SIGC*SQRT_H
#define INVBN  0.99950037468877324f    // 1/sqrt(1+1e-3)
#define QF     0.96078943915232318f    // exp(100*(R-MU)*h)
#define DISC   0.98019867330675525f    // exp(-R*T)
#define CURT   0.005f

typedef __attribute__((ext_vector_type(8))) short short8;
typedef __attribute__((ext_vector_type(4))) float floatx4;
typedef __attribute__((ext_vector_type(4))) unsigned uintx4;
typedef __attribute__((ext_vector_type(2))) unsigned uintx2;

__device__ __forceinline__ unsigned toSort(float f){
    unsigned u = __float_as_uint(f);
    return (u & 0x80000000u) ? ~u : (u | 0x80000000u);
}
__device__ __forceinline__ float fromSort(unsigned s){
    unsigned u = (s & 0x80000000u) ? (s & 0x7fffffffu) : ~s;
    return __uint_as_float(u);
}
__device__ __forceinline__ unsigned short bfc(float f){   // f32->bf16 RNE
    unsigned u = __float_as_uint(f);
    unsigned r = u + 0x7FFFu + ((u >> 16) & 1u);
    return (unsigned short)(r >> 16);
}
__device__ __forceinline__ float red16(float v){
    float t;
    t = __int_as_float(__builtin_amdgcn_update_dpp(0, __float_as_int(v), 0x128, 0xF, 0xF, false)); v += t;
    t = __int_as_float(__builtin_amdgcn_update_dpp(0, __float_as_int(v), 0x124, 0xF, 0xF, false)); v += t;
    t = __int_as_float(__builtin_amdgcn_update_dpp(0, __float_as_int(v), 0x122, 0xF, 0xF, false)); v += t;
    t = __int_as_float(__builtin_amdgcn_update_dpp(0, __float_as_int(v), 0x121, 0xF, 0xF, false)); v += t;
    return v;
}
__device__ __forceinline__ float tanh_fast(float z){
    z = fminf(9.f, fmaxf(-9.f, z));
    float e = __expf(2.f * z);
    return __fdividef(e - 1.f, e + 1.f);
}
__device__ __forceinline__ unsigned laneid(){
    return __builtin_amdgcn_mbcnt_hi(~0u, __builtin_amdgcn_mbcnt_lo(~0u, 0u));
}
// wave-aggregated LDS histogram add (handles heavy same-bin concentration)
__device__ __forceinline__ void aggAdd(unsigned* hist, unsigned bin){
    bool pending = true;
    unsigned lid = laneid();
    while (__any(pending)){
        if (pending){
            unsigned lead = (unsigned)__builtin_amdgcn_readfirstlane((int)bin);
            if (bin == lead){
                unsigned long long m = __ballot(1);
                if (lid == (unsigned)__builtin_ctzll(m))
                    atomicAdd(&hist[lead], (unsigned)__popcll(m));
                pending = false;
            }
        }
    }
}
// exclusive wave scan of unsigned (width 64)
__device__ __forceinline__ unsigned wexscan(unsigned s, int l){
    unsigned incl = s;
#pragma unroll
    for (int off=1; off<64; off<<=1){
        unsigned t2 = __shfl_up(incl, off, 64);
        if (l >= off) incl += t2;
    }
    return incl - s;
}

// ---------------------------------------------------------------------------
// K0: fold BN scale/shift into weights, pre-convert to bf16.
// 30 independent blocks: bid = p*3 + m, m in {W2, W3, Wout}.
// Per-output arithmetic identical to the fused version.
// ---------------------------------------------------------------------------
__global__ __launch_bounds__(256,1) void k_conv(
    const float* __restrict__ uWh, const float* __restrict__ ubh,
    const float* __restrict__ bng, const float* __restrict__ bnb,
    const float* __restrict__ uWout, const float* __restrict__ ubout,
    unsigned short* __restrict__ Wc2, unsigned short* __restrict__ Wc3,
    unsigned short* __restrict__ Wco,
    float* __restrict__ b2f, float* __restrict__ b3f, float* __restrict__ bof)
{
    const int bid = blockIdx.x;
    const int p = bid / 3, m = bid % 3;
    const int t = threadIdx.x;
    __shared__ float gs[64], es[64];
    __shared__ float red4[64][4];
    __shared__ float red8[32][8];
    if (t < 64){
        gs[t] = INVBN * bng[(p*3+m)*64 + t];
        es[t] = bnb[(p*3+m)*64 + t];
    }
    __syncthreads();
    if (m < 2){
        unsigned short* Wt = (m == 0) ? Wc2 : Wc3;
        const int j = t & 63, kq = t >> 6;
        float bs = 0.f;
        for (int k = kq*16; k < kq*16+16; ++k){
            float w = uWh[((size_t)(p*2+m)*64 + k)*64 + j];
            bs += w * es[k];
            Wt[(size_t)(p*64 + j)*64 + k] = bfc(w * gs[k]);
        }
        red4[j][kq] = bs;
        __syncthreads();
        if (t < 64){
            float v = ubh[(p*3+m+1)*64 + t]
                    + red4[t][0]+red4[t][1]+red4[t][2]+red4[t][3];
            if (m == 0) b2f[p*64 + t] = v; else b3f[p*64 + t] = v;
        }
    } else {
        const int d = t & 31, kq = t >> 5;
        float bs = 0.f;
        for (int k = kq*8; k < kq*8+8; ++k){
            float w = (d < 20) ? uWout[((size_t)p*64 + k)*20 + d] : 0.f;
            bs += w * es[k];
            Wco[(size_t)(p*32 + d)*64 + k] = bfc(w * gs[k]);
        }
        red8[d][kq] = bs;
        __syncthreads();
        if (t < 32){
            float s = 0.f;
            for (int q=0;q<8;q++) s += red8[t][q];
            bof[p*32 + t] = ((t < 20) ? ubout[p*20 + t] : 0.f) + s;
        }
    }
}

// ---------------------------------------------------------------------------
// K1: SDE scan + fused option-head partial reduction.
// 16 lanes/row; phase-invariant sum(u) hoisted; invS tracking (no divides);
// phase-batched dW register prefetch.
// NEW this round: MFMA B-fragments read DIRECTLY from global (L2-resident,
// identical bytes to the old LDS-staged copies) — no WtA/WtB/WtO staging.
// Input layer computed from register x (all 16 lanes of a row hold
// bit-identical x via the red16 ror-butterfly) — no xL broadcast, one
// fewer barrier per phase (4 instead of 5).
// ---------------------------------------------------------------------------
__global__ __launch_bounds__(256, 4) void k_sim(
    const float* __restrict__ x_in, const float* __restrict__ S0,
    const float* __restrict__ dW,
    const float* __restrict__ u0W, const float* __restrict__ u0b,
    const float* __restrict__ uWin, const float* __restrict__ ubh,
    const unsigned short* __restrict__ Wc2, const unsigned short* __restrict__ Wc3,
    const unsigned short* __restrict__ Wco,
    const float* __restrict__ b2f, const float* __restrict__ b3f,
    const float* __restrict__ bof,
    const float* __restrict__ optW, const float* __restrict__ optb,
    const float* __restrict__ KW, const float* __restrict__ Kb,
    float* __restrict__ xsim, float* __restrict__ daccs,
    float* __restrict__ Sfin, float* __restrict__ partial)
{
    __shared__ unsigned short hA[16*72];
    __shared__ unsigned short hB[16*72];
    __shared__ float aL[16*20];
    __shared__ float pacc[48];

    const int tid = threadIdx.x;
    const int rl  = tid >> 4;
    const int la  = tid & 15;
    const int b   = blockIdx.x * 16 + rl;
    const int a2  = 16 + (la & 3);
    const bool act2 = (la < 4);
    const int w2 = tid >> 6;
    const int lw = tid & 63;
    const int cn = lw & 15;
    const int qq = lw >> 4;

    float x = x_in[b];
    const float S00 = S0[b*20 + la];
    const float S01 = S0[b*20 + a2];
    float iS0 = __fdividef(1.f, S00);
    float iS1 = __fdividef(1.f, S01);
    float al0 = fmaf(x, u0W[la], u0b[la]);
    float al1 = act2 ? fmaf(x, u0W[a2], u0b[a2]) : 0.f;
    float Nm10 = al0 * iS0, Nm11 = al1 * iS1;   // seeds n=1 delta to exactly 0
    float dacc0 = 0.f, dacc1 = 0.f;

    const size_t STEP = (size_t)B_TOT * 20;
    const float* pA = dW + (size_t)b*20 + la;
    const float* pB = dW + (size_t)b*20 + a2;

    // phase-0 prefetch: steps 1..10 use dW[0..9]
    float dA[10], dB[10];
#pragma unroll
    for (int s = 0; s < 10; ++s){
        dA[s] = pA[(size_t)s*STEP];
        dB[s] = pB[(size_t)s*STEP];
    }
    const float XA = 1.f + RH;

    for (int p = 0; p < 10; ++p){
        const float su = red16(al0 + al1);
        const float Cp = su * (MUH - RH);
#pragma unroll
        for (int s = 0; s < 10; ++s){
            float np0 = al0 * iS0;
            float np1 = al1 * iS1;
            dacc0 += fabsf(np0 - Nm10);
            dacc1 += fabsf(np1 - Nm11);
            Nm10 = np0; Nm11 = np1;
            float dot = red16(fmaf(al0, dA[s], al1 * dB[s]));
            x = fmaf(SSC, dot, fmaf(x, XA, Cp));
            iS0 *= __expf(fmaf(-SSC, dA[s], -DRIFT));
            iS1 *= __expf(fmaf(-SSC, dB[s], -DRIFT));
        }
        if (p < 9){
            // issue next phase's dW loads NOW — they ride out the MLP section
            {
                const float* qA = pA + (size_t)(p+1)*10*STEP;
                const float* qB = pB + (size_t)(p+1)*10*STEP;
#pragma unroll
                for (int s = 0; s < 10; ++s){
                    dA[s] = qA[(size_t)s*STEP];
                    dB[s] = qB[(size_t)s*STEP];
                }
            }
            const int col = 16*w2 + cn;
            // B-fragments straight from global (L2-resident; bytes identical
            // to the old LDS-staged WtA/WtB)
            const unsigned short* W2p = Wc2 + (size_t)p*4096 + (size_t)col*64;
            const unsigned short* W3p = Wc3 + (size_t)p*4096 + (size_t)col*64;
            short8 wA0 = *reinterpret_cast<const short8*>(W2p + qq*8);
            short8 wA1 = *reinterpret_cast<const short8*>(W2p + 32 + qq*8);
            short8 wB0 = *reinterpret_cast<const short8*>(W3p + qq*8);
            short8 wB1 = *reinterpret_cast<const short8*>(W3p + 32 + qq*8);
            {   // input layer from register x: this thread computes units
                // la*4..la*4+3 of ITS OWN row rl (x identical across the row)
                const float* Wi = uWin + p*64;
                const float* b0 = ubh + (p*3+0)*64;
                unsigned short h4[4];
#pragma unroll
                for (int i=0;i<4;i++)
                    h4[i] = bfc(fmaxf(fmaf(x, Wi[la*4+i], b0[la*4+i]), 0.f));
                uintx2 hw;
                hw.x = (unsigned)h4[0] | ((unsigned)h4[1] << 16);
                hw.y = (unsigned)h4[2] | ((unsigned)h4[3] << 16);
                *reinterpret_cast<uintx2*>(&hA[rl*72 + la*4]) = hw;
            }
            __syncthreads();
            {   // L2: hA x wA -> hB (relu only; BN folded)
                float bias = b2f[p*64 + col];
                floatx4 c = {bias, bias, bias, bias};
                short8 a0 = *reinterpret_cast<const short8*>(&hA[cn*72 + qq*8]);
                short8 a1 = *reinterpret_cast<const short8*>(&hA[cn*72 + 32 + qq*8]);
                c = __builtin_amdgcn_mfma_f32_16x16x32_bf16(a0, wA0, c, 0, 0, 0);
                c = __builtin_amdgcn_mfma_f32_16x16x32_bf16(a1, wA1, c, 0, 0, 0);
#pragma unroll
                for (int i=0;i<4;i++)
                    hB[(qq*4+i)*72 + col] = bfc(fmaxf(c[i], 0.f));
            }
            __syncthreads();
            {   // L3: hB x wB -> hA
                float bias = b3f[p*64 + col];
                floatx4 c = {bias, bias, bias, bias};
                short8 a0 = *reinterpret_cast<const short8*>(&hB[cn*72 + qq*8]);
                short8 a1 = *reinterpret_cast<const short8*>(&hB[cn*72 + 32 + qq*8]);
                c = __builtin_amdgcn_mfma_f32_16x16x32_bf16(a0, wB0, c, 0, 0, 0);
                c = __builtin_amdgcn_mfma_f32_16x16x32_bf16(a1, wB1, c, 0, 0, 0);
#pragma unroll
                for (int i=0;i<4;i++)
                    hA[(qq*4+i)*72 + col] = bfc(fmaxf(c[i], 0.f));
            }
            __syncthreads();
            if (w2 < 2){   // out layer: hA x Wco -> aL
                const unsigned short* Wop = Wco + (size_t)p*2048 + (size_t)col*64;
                short8 wO0 = *reinterpret_cast<const short8*>(Wop + qq*8);
                short8 wO1 = *reinterpret_cast<const short8*>(Wop + 32 + qq*8);
                float bias = bof[p*32 + col];
                floatx4 c = {bias, bias, bias, bias};
                short8 a0 = *reinterpret_cast<const short8*>(&hA[cn*72 + qq*8]);
                short8 a1 = *reinterpret_cast<const short8*>(&hA[cn*72 + 32 + qq*8]);
                c = __builtin_amdgcn_mfma_f32_16x16x32_bf16(a0, wO0, c, 0, 0, 0);
                c = __builtin_amdgcn_mfma_f32_16x16x32_bf16(a1, wO1, c, 0, 0, 0);
                if (col < 20){
#pragma unroll
                    for (int i=0;i<4;i++) aL[(qq*4+i)*20 + col] = c[i];
                }
            }
            __syncthreads();
            al0 = aL[rl*20 + la];
            al1 = act2 ? aL[rl*20 + a2] : 0.f;
        }
    }

    // --- per-row outputs ---
    float Sf0 = __fdividef(1.f, iS0);
    float Sf1 = __fdividef(1.f, iS1);
    float ds = red16(dacc0 + dacc1);
    if (la == 0){ xsim[b] = x; daccs[b] = ds; }
    Sfin[b*20 + la] = Sf0;
    if (act2) Sfin[b*20 + a2] = Sf1;

    // --- fused option-head block partials ---
    if (tid < 48) pacc[tid] = 0.f;
    __syncthreads();
    float e1v = __expf(fmaf(x, optW[la],    optb[la]));
    float e2v = __expf(fmaf(x, optW[16+la], optb[16+la]));
    float e3v = (la <= 8) ? __expf(fmaf(x, optW[32+la], optb[32+la])) : 0.f;
    float sAll = red16(e1v + e2v + e3v);
    float e40 = __shfl(e3v, (lw & 48) + 8, 64);
    float afrac = __fdividef(sAll - e40, sAll);
    float kc0 = fmaf(0.25f, tanh_fast(fmaf(x, KW[la],    Kb[la]   )), 1.f);
    float kp0 = fmaf(0.25f, tanh_fast(fmaf(x, KW[20+la], Kb[20+la])), 1.f);
    float sq0 = QF * __fdividef(Sf0, S00);
    atomicAdd(&pacc[la],    fmaxf(sq0 - kc0, 0.f));
    atomicAdd(&pacc[20+la], fmaxf(kp0 - sq0, 0.f));
    if (act2){
        float kc1 = fmaf(0.25f, tanh_fast(fmaf(x, KW[a2],    Kb[a2]   )), 1.f);
        float kp1 = fmaf(0.25f, tanh_fast(fmaf(x, KW[20+a2], Kb[20+a2])), 1.f);
        float sq1 = QF * __fdividef(Sf1, S01);
        atomicAdd(&pacc[a2],    fmaxf(sq1 - kc1, 0.f));
        atomicAdd(&pacc[20+a2], fmaxf(kp1 - sq1, 0.f));
    }
    if (la == 0){
        atomicAdd(&pacc[40], afrac);
        atomicAdd(&pacc[41], fmaxf(Sf0 - kc0, 0.f));
    }
    __syncthreads();
    if (tid < 48) partial[tid*1024 + blockIdx.x] = pacc[tid];
}

// ---------------------------------------------------------------------------
// K2: reduce partials; per-row final wealth; losses 5..7
// ---------------------------------------------------------------------------
__global__ __launch_bounds__(256,1) void k_final(
    const float* __restrict__ x_in,
    const float* __restrict__ optW, const float* __restrict__ optb,
    const float* __restrict__ KW, const float* __restrict__ Kb,
    const float* __restrict__ Sfin, const float* __restrict__ xsim,
    const float* __restrict__ daccs, const float* __restrict__ partial,
    float* __restrict__ xfin, float* __restrict__ out)
{
    __shared__ float accL[48];
    __shared__ float tmp[48][4];
    const int t = threadIdx.x;
    if (t < 192){
        const int r = t >> 2, q = t & 3;
        const floatx4* s4 = (const floatx4*)(partial + r*1024 + q*256);
        float acc = 0.f;
#pragma unroll 4
        for (int i=0;i<64;i++){ floatx4 v = s4[i]; acc += v[0]+v[1]+v[2]+v[3]; }
        tmp[r][q] = acc;
    }
    __syncthreads();
    if (t < 48) accL[t] = tmp[t][0]+tmp[t][1]+tmp[t][2]+tmp[t][3];
    __syncthreads();

    const int b = blockIdx.x*256 + t;
    const float x = x_in[b];
    float e[41]; float m = -1e30f;
#pragma unroll
    for (int k=0;k<41;k++){ e[k] = fmaf(x, optW[k], optb[k]); m = fmaxf(m, e[k]); }
    float s = 0.f;
#pragma unroll
    for (int k=0;k<41;k++){ e[k] = __expf(e[k]-m); s += e[k]; }
    const float invs = 1.f / s;
    const float invB = 1.f / (float)B_TOT;
    const float rescale = 1.f - accL[40]*invB;
    float pay = 0.f, k01 = 0.f;
#pragma unroll
    for (int d=0; d<20; d++){
        float Sv = Sfin[(size_t)b*20 + d];
        float kc = fmaf(0.25f, tanh_fast(fmaf(x, KW[d],    Kb[d]   )), 1.f);
        float kp = fmaf(0.25f, tanh_fast(fmaf(x, KW[20+d], Kb[20+d])), 1.f);
        float C0d = DISC * accL[d]    * invB;
        float P0d = DISC * accL[20+d] * invB;
        pay += (e[d]*invs)    * fmaxf(Sv - kc, 0.f) / C0d;
        pay += (e[20+d]*invs) * fmaxf(kp - Sv, 0.f) / P0d;
        if (d == 1) k01 = kc;
    }
    float xf = rescale * xsim[b] - CURT * rescale * daccs[b] + pay;
    xfin[b] = xf;
    if (b == 0){
        out[4] = accL[41] / (DISC * accL[0]);
        out[5] = k01;
        out[6] = rescale;
    }
}

// ---------------------------------------------------------------------------
// K3: tail — keys in LDS; 3-level (12/10/10) radix select; single-wave
// parallel scans (shfl_up + ballot owner-find + cooperative bin resolve).
// ---------------------------------------------------------------------------
__global__ __launch_bounds__(1024,1) void k_tail(
    const float* __restrict__ xfin, float* __restrict__ out)
{
    __shared__ unsigned keys[16384];
    __shared__ unsigned hist[4096];
    __shared__ unsigned b1[4], r1[4], b2[4], r2[4];
    __shared__ int rep1[4], rep2[4];
    __shared__ float vals[4];
    __shared__ float pp[2];
    __shared__ double rdd[16][2];
    __shared__ float rff[16][2];
    __shared__ unsigned ruu[16][2];
    const int tid = threadIdx.x;
    const unsigned ranks[4] = {819u, 820u, 15563u, 15564u};

#pragma unroll
    for (int i=0;i<16;i++) keys[tid + i*1024] = toSort(xfin[tid + i*1024]);
#pragma unroll
    for (int i=0;i<4;i++) hist[tid + i*1024] = 0u;
    __syncthreads();

    // ---- Level 1: top 12 bits (wave-aggregated: keys concentrate) ----
#pragma unroll
    for (int i=0;i<16;i++) aggAdd(hist, keys[tid + i*1024] >> 20);
    __syncthreads();
    if (tid < 64){
        const int l = tid;
        unsigned s = 0;
#pragma unroll
        for (int i=0;i<16;i++){
            const int j = (i + l) & 15;
            uintx4 v = *reinterpret_cast<const uintx4*>(&hist[l*64 + j*4]);
            s += v.x + v.y + v.z + v.w;
        }
        const unsigned cumb = wexscan(s, l);
#pragma unroll
        for (int t=0;t<4;t++){
            const unsigned r = ranks[t];
            bool own = (r >= cumb) && (r < cumb + s);
            unsigned long long m = __ballot(own);
            int owner = (int)__builtin_ctzll(m);
            unsigned cb = (unsigned)__shfl((int)cumb, owner, 64);
            unsigned rr = r - cb;
            unsigned c = hist[owner*64 + l];
            unsigned cex = wexscan(c, l);
            if (rr >= cex && rr < cex + c){
                b1[t] = (unsigned)(owner*64 + l);
                r1[t] = rr - cex;
            }
        }
    }
    __syncthreads();
    if (tid == 0){
#pragma unroll
        for (int t=0;t<4;t++)
            rep1[t] = (t>0 && b1[t]==b1[t-1]) ? rep1[t-1] : t;
    }
    __syncthreads();

    // ---- Level 2: bits 19..10 (dedup planes) ----
#pragma unroll
    for (int i=0;i<4;i++) hist[tid + i*1024] = 0u;
    __syncthreads();
#pragma unroll
    for (int i=0;i<16;i++){
        unsigned k = keys[tid + i*1024];
        unsigned h12 = k >> 20, mid = (k >> 10) & 1023u;
#pragma unroll
        for (int t=0;t<4;t++)
            if (rep1[t]==t && h12 == b1[t]) atomicAdd(&hist[t*1024 + (int)mid], 1u);
    }
    __syncthreads();
    if (tid < 256){
        const int p = tid >> 6, l = tid & 63;
        const unsigned* h = hist + rep1[p]*1024;
        unsigned s = 0;
#pragma unroll
        for (int i=0;i<4;i++){
            const int j = (i + l) & 3;
            uintx4 v = *reinterpret_cast<const uintx4*>(&h[l*16 + j*4]);
            s += v.x + v.y + v.z + v.w;
        }
        const unsigned cumb = wexscan(s, l);
        const unsigned r = r1[p];
        bool own = (r >= cumb) && (r < cumb + s);
        unsigned long long m = __ballot(own);
        int owner = (int)__builtin_ctzll(m);
        unsigned cb = (unsigned)__shfl((int)cumb, owner, 64);
        unsigned rr = r - cb;
        unsigned c = (l < 16) ? h[owner*16 + l] : 0u;
        unsigned cex = wexscan(c, l);
        if (l < 16 && rr >= cex && rr < cex + c){
            b2[p] = (unsigned)(owner*16 + l);
            r2[p] = rr - cex;
        }
    }
    __syncthreads();
    if (tid == 0){
#pragma unroll
        for (int t=0;t<4;t++)
            rep2[t] = (t>0 && b1[t]==b1[t-1] && b2[t]==b2[t-1]) ? rep2[t-1] : t;
    }
    __syncthreads();

    // ---- Level 3: bits 9..0 ----
#pragma unroll
    for (int i=0;i<4;i++) hist[tid + i*1024] = 0u;
    __syncthreads();
#pragma unroll
    for (int i=0;i<16;i++){
        unsigned k = keys[tid + i*1024];
        unsigned top22 = k >> 10;
#pragma unroll
        for (int t=0;t<4;t++)
            if (rep2[t]==t && top22 == ((b1[t]<<10) | b2[t]))
                atomicAdd(&hist[t*1024 + (int)(k & 1023u)], 1u);
    }
    __syncthreads();
    if (tid < 256){
        const int p = tid >> 6, l = tid & 63;
        const unsigned* h = hist + rep2[p]*1024;
        unsigned s = 0;
#pragma unroll
        for (int i=0;i<4;i++){
            const int j = (i + l) & 3;
            uintx4 v = *reinterpret_cast<const uintx4*>(&h[l*16 + j*4]);
            s += v.x + v.y + v.z + v.w;
        }
        const unsigned cumb = wexscan(s, l);
        const unsigned r = r2[p];
        bool own = (r >= cumb) && (r < cumb + s);
        unsigned long long m = __ballot(own);
        int owner = (int)__builtin_ctzll(m);
        unsigned cb = (unsigned)__shfl((int)cumb, owner, 64);
        unsigned rr = r - cb;
        unsigned c = (l < 16) ? h[owner*16 + l] : 0u;
        unsigned cex = wexscan(c, l);
        if (l < 16 && rr >= cex && rr < cex + c){
            vals[p] = fromSort((b1[p]<<20) | (b2[p]<<10) | (unsigned)(owner*16 + l));
        }
    }
    __syncthreads();
    if (tid == 0){
        pp[0] = vals[0] + 0.15f*(vals[1]-vals[0]);
        pp[1] = vals[2] + 0.85f*(vals[3]-vals[2]);
    }
    __syncthreads();

    // ---- Reductions ----
    const float p5 = pp[0], p95 = pp[1];
    double sv = 0.0, sq = 0.0;
    float lo = 0.f, hi = 0.f;
    unsigned lc = 0u, hc = 0u;
#pragma unroll
    for (int i=0;i<16;i++){
        float v = fromSort(keys[tid + i*1024]);
        sv += (double)v; sq += (double)v*(double)v;
        if (v < p5){ lo += v; lc++; }
        if (v > p95){ hi += v; hc++; }
    }
    for (int o=1;o<64;o<<=1){
        sv += __shfl_xor(sv,o,64);
        sq += __shfl_xor(sq,o,64);
        lo += __shfl_xor(lo,o,64);
        hi += __shfl_xor(hi,o,64);
        lc += __shfl_xor(lc,o,64);
        hc += __shfl_xor(hc,o,64);
    }
    const int wv = tid >> 6, ln = tid & 63;
    if (ln == 0){ rdd[wv][0]=sv; rdd[wv][1]=sq; rff[wv][0]=lo; rff[wv][1]=hi;
                  ruu[wv][0]=lc; ruu[wv][1]=hc; }
    __syncthreads();
    if (tid == 0){
        double a=0, bq=0; float c=0, d=0; unsigned e2=0, f2=0;
        for (int i=0;i<16;i++){ a+=rdd[i][0]; bq+=rdd[i][1]; c+=rff[i][0];
                                 d+=rff[i][1]; e2+=ruu[i][0]; f2+=ruu[i][1]; }
        const double N = (double)B_TOT;
        double mean = a / N;
        out[0] = (float)(-mean);
        out[1] = (float)(bq/N - mean*mean);
        out[2] = -c / (float)(e2 ? e2 : 1u);
        out[3] = -d / (float)(f2 ? f2 : 1u);
    }
}

extern "C" void kernel_launch(void* const* d_in, const int* in_sizes, int n_in,
                              void* d_out, int out_size, void* d_ws, size_t ws_size,
                              hipStream_t stream)
{
    const float* x_in = (const float*)d_in[0];
    const float* S0   = (const float*)d_in[1];
    const float* dW   = (const float*)d_in[2];
    const float* u0W  = (const float*)d_in[3];
    const float* u0b  = (const float*)d_in[4];
    const float* uWin = (const float*)d_in[5];
    const float* uWh  = (const float*)d_in[6];
    const float* ubh  = (const float*)d_in[7];
    const float* bng  = (const float*)d_in[8];
    const float* bnb  = (const float*)d_in[9];
    const float* uWout= (const float*)d_in[10];
    const float* ubout= (const float*)d_in[11];
    const float* optW = (const float*)d_in[12];
    const float* optb = (const float*)d_in[13];
    const float* KW   = (const float*)d_in[14];
    const float* Kb   = (const float*)d_in[15];
    float* out = (float*)d_out;
    float* ws  = (float*)d_ws;

    // float-indexed workspace offsets
    const size_t OFF_XSIM = 0;          // 16384
    const size_t OFF_DACC = 16384;      // 16384
    const size_t OFF_S    = 32768;      // 327680
    const size_t OFF_XFIN = 360448;     // 16384
    const size_t OFF_PART = 376832;     // 48*1024
    const size_t OFF_WC2  = 425984;     // 10*64*64 bf16 = 20480 floats
    const size_t OFF_WC3  = 446464;     // 20480
    const size_t OFF_WCO  = 466944;     // 10*32*64 bf16 = 10240 floats
    const size_t OFF_B2F  = 477184;     // 640
    const size_t OFF_B3F  = 477824;     // 640
    const size_t OFF_BOF  = 478464;     // 320

    unsigned short* Wc2 = (unsigned short*)(ws + OFF_WC2);
    unsigned short* Wc3 = (unsigned short*)(ws + OFF_WC3);
    unsigned short* Wco = (unsigned short*)(ws + OFF_WCO);

    k_conv<<<30,256,0,stream>>>(uWh, ubh, bng, bnb, uWout, ubout,
                                Wc2, Wc3, Wco,
                                ws+OFF_B2F, ws+OFF_B3F, ws+OFF_BOF);
    k_sim<<<1024,256,0,stream>>>(x_in, S0, dW, u0W, u0b, uWin, ubh,
                                 Wc2, Wc3, Wco,
                                 ws+OFF_B2F, ws+OFF_B3F, ws+OFF_BOF,
                                 optW, optb, KW, Kb,
                                 ws+OFF_XSIM, ws+OFF_DACC, ws+OFF_S, ws+OFF_PART);
    k_final<<<64,256,0,stream>>>(x_in, optW, optb, KW, Kb,
                                 ws+OFF_S, ws+OFF_XSIM, ws+OFF_DACC, ws+OFF_PART,
                                 ws+OFF_XFIN, out);
    k_tail<<<1,1024,0,stream>>>(ws+OFF_XFIN, out);
}